// Round 4
// baseline (185.287 us; speedup 1.0000x reference)
//
#include <hip/hip_runtime.h>
#include <hip/hip_bf16.h>

// PINN via MFMA: per-wave 32 samples. State (h,hx,hxx) as bf16 B-fragments in
// registers; weights as block-shared LDS A-fragments (hi/lo split for the value
// stream); C[ch][samp] orientation shares A-frags across the 3 streams.
// out = u - dt*(f @ alpha^T). Packing via cvt_pk (compiler-fused), direct
// global stores from C-layout, 48KB LDS -> 3 blocks/CU.

#define NPTS 262144
#define HW   50
#define Q    100
#define BLK  256
#define WAVES 4
#define SPW  32
#define SPB  128
#define NBLK (NPTS / SPB)

typedef float f32x4 __attribute__((ext_vector_type(4)));
typedef short bf16x8 __attribute__((ext_vector_type(8)));
typedef unsigned int u32x4 __attribute__((ext_vector_type(4)));

#define MFMA __builtin_amdgcn_mfma_f32_16x16x32_bf16

__device__ __forceinline__ unsigned int pack_bf2(float a, float b) {
    __hip_bfloat162 h = __float22bfloat162_rn(make_float2(a, b));
    unsigned int u;
    __builtin_memcpy(&u, &h, 4);   // bit-extract; __hip_bfloat162 not trivially copyable for bit_cast
    return u;
}
__device__ __forceinline__ float lo_f(unsigned int p) {   // low bf16 as float
    return __builtin_bit_cast(float, p << 16);
}
__device__ __forceinline__ float hi_f(unsigned int p) {   // high bf16 as float
    return __builtin_bit_cast(float, p & 0xffff0000u);
}
__device__ __forceinline__ float fast_tanh(float z) {
    float e = __expf(2.0f * z);
    return 1.0f - __fdividef(2.0f, e + 1.0f);
}

// Build A-fragments into LDS, frag-ready for ds_read_b128.
// A[m][k] = TRANS ? src[k*ld + m+mbase] : src[(m+mbase)*ld + k], zero-padded.
// hi slot fid = kt*NMT+mt at wfrag + fid*1024 + lane*16; lo at +NF*1024.
template<int NMT, int NKT, bool WANT_LO, bool TRANS>
__device__ __forceinline__ void prep_frags(unsigned char* wfrag, const float* __restrict__ src,
                                           int kmax, int mbase, int mmax, int ld, int tid)
{
    constexpr int NF = NMT * NKT;
    for (int p = tid; p < NF * 64; p += BLK) {
        int ln  = p & 63;
        int fid = p >> 6;
        int kt  = fid / NMT;           // NMT compile-time -> magic mul
        int mt  = fid - kt * NMT;
        int m   = mbase + mt * 16 + (ln & 15);
        int kb  = kt * 32 + (ln >> 4) * 8;
        bool mv = (m < mmax);
        unsigned int hw[4], lw[4];
#pragma unroll
        for (int jj = 0; jj < 4; ++jj) {
            int k0 = kb + 2 * jj, k1 = k0 + 1;
            float v0 = (mv && k0 < kmax) ? (TRANS ? src[k0 * ld + m] : src[m * ld + k0]) : 0.0f;
            float v1 = (mv && k1 < kmax) ? (TRANS ? src[k1 * ld + m] : src[m * ld + k1]) : 0.0f;
            unsigned int h = pack_bf2(v0, v1);
            hw[jj] = h;
            if (WANT_LO)
                lw[jj] = pack_bf2(v0 - lo_f(h), v1 - hi_f(h));
        }
        *(uint4*)(wfrag + fid * 1024 + ln * 16) = make_uint4(hw[0], hw[1], hw[2], hw[3]);
        if (WANT_LO)
            *(uint4*)(wfrag + (NF + fid) * 1024 + ln * 16) = make_uint4(lw[0], lw[1], lw[2], lw[3]);
    }
}

__global__ void __launch_bounds__(BLK, 3)
pinn_mfma(const float* __restrict__ W0, const float* __restrict__ b0,
          const float* __restrict__ W1, const float* __restrict__ b1,
          const float* __restrict__ W2, const float* __restrict__ b2,
          const float* __restrict__ W3, const float* __restrict__ b3,
          const float* __restrict__ W4, const float* __restrict__ b4,
          const float* __restrict__ W5, const float* __restrict__ b5,
          const float* __restrict__ x, const float* __restrict__ lam1p,
          const float* __restrict__ lam2p, const float* __restrict__ alpha,
          const float* __restrict__ dtp, float* __restrict__ out)
{
    __shared__ __align__(16) unsigned char wfrag[16 * 1024];
    __shared__ __align__(16) unsigned char statebuf[WAVES][8192];

    const int tid  = threadIdx.x;
    const int w    = tid >> 6;
    const int lane = tid & 63;
    const int l15  = lane & 15;
    const int g    = lane >> 4;
    const int sbase = blockIdx.x * SPB + w * SPW;

    unsigned char* st0 = &statebuf[w][0];
    unsigned char* st1 = &statebuf[w][4096];
    const unsigned char* wfl = wfrag + lane * 16;
    const int swz = (l15 & 7) << 4;   // samp&7 == l15&7

    const f32x4 Z4 = {0.0f, 0.0f, 0.0f, 0.0f};

    // persistent state B-fragments: B[k=ch][n=samp], elem j -> ch = 32kt+8g+j
    bf16x8 Bh_hi[2][2], Bh_lo[2][2], Bx[2][2], Bxx[2][2];

    // ---------- layer 0: 1 -> 50 (analytic, elementwise) ----------
    {
        float xv[2];
        xv[0] = x[sbase + l15];
        xv[1] = x[sbase + 16 + l15];
#pragma unroll
        for (int kt = 0; kt < 2; ++kt) {
            float wv[8], bv[8];
#pragma unroll
            for (int j = 0; j < 8; ++j) {
                int ch = kt * 32 + g * 8 + j;
                wv[j] = (ch < HW) ? W0[ch] : 0.0f;
                bv[j] = (ch < HW) ? b0[ch] : 0.0f;
            }
#pragma unroll
            for (int nt = 0; nt < 2; ++nt) {
                u32x4 uh, ul, ux, uxx;
#pragma unroll
                for (int jp = 0; jp < 4; ++jp) {
                    float t0 = fast_tanh(fmaf(xv[nt], wv[2*jp],   bv[2*jp]));
                    float t1 = fast_tanh(fmaf(xv[nt], wv[2*jp+1], bv[2*jp+1]));
                    float s0 = 1.0f - t0 * t0, s1 = 1.0f - t1 * t1;
                    float hx0 = s0 * wv[2*jp],   hx1 = s1 * wv[2*jp+1];
                    float hxx0 = -2.0f * t0 * hx0 * wv[2*jp];
                    float hxx1 = -2.0f * t1 * hx1 * wv[2*jp+1];
                    unsigned int h = pack_bf2(t0, t1);
                    uh[jp]  = h;
                    ul[jp]  = pack_bf2(t0 - lo_f(h), t1 - hi_f(h));
                    ux[jp]  = pack_bf2(hx0, hx1);
                    uxx[jp] = pack_bf2(hxx0, hxx1);
                }
                Bh_hi[kt][nt] = __builtin_bit_cast(bf16x8, uh);
                Bh_lo[kt][nt] = __builtin_bit_cast(bf16x8, ul);
                Bx[kt][nt]    = __builtin_bit_cast(bf16x8, ux);
                Bxx[kt][nt]   = __builtin_bit_cast(bf16x8, uxx);
            }
        }
    }

    // ---------- 4 hidden layers 50 -> 50 ----------
    for (int L = 0; L < 4; ++L) {
        const float *Wl, *bl;
        if      (L == 0) { Wl = W1; bl = b1; }
        else if (L == 1) { Wl = W2; bl = b2; }
        else if (L == 2) { Wl = W3; bl = b3; }
        else             { Wl = W4; bl = b4; }

        __syncthreads();
        prep_frags<4, 2, true, true>(wfrag, Wl, HW, 0, HW, HW, tid);
        __syncthreads();

        float bb[4][4];
#pragma unroll
        for (int mt = 0; mt < 4; ++mt)
#pragma unroll
            for (int r = 0; r < 4; ++r) {
                int ch = mt * 16 + g * 4 + r;
                bb[mt][r] = (ch < HW) ? bl[ch] : 0.0f;
            }

        // accumulators; at pre-seeded with bias (saves the add before tanh)
        f32x4 at[4][2], ax[4][2], axx[4][2];
#pragma unroll
        for (int mt = 0; mt < 4; ++mt)
#pragma unroll
            for (int nt = 0; nt < 2; ++nt) {
#pragma unroll
                for (int r = 0; r < 4; ++r) at[mt][nt][r] = bb[mt][r];
                ax[mt][nt] = Z4; axx[mt][nt] = Z4;
            }

#pragma unroll
        for (int kt = 0; kt < 2; ++kt) {
#pragma unroll
            for (int mt = 0; mt < 4; ++mt) {
                bf16x8 Ahi = *(const bf16x8*)(wfl + (kt * 4 + mt) * 1024);
                bf16x8 Alo = *(const bf16x8*)(wfl + (8 + kt * 4 + mt) * 1024);
#pragma unroll
                for (int nt = 0; nt < 2; ++nt) {
                    at[mt][nt]  = MFMA(Ahi, Bh_hi[kt][nt], at[mt][nt], 0, 0, 0);
                    at[mt][nt]  = MFMA(Ahi, Bh_lo[kt][nt], at[mt][nt], 0, 0, 0);
                    at[mt][nt]  = MFMA(Alo, Bh_hi[kt][nt], at[mt][nt], 0, 0, 0);
                    ax[mt][nt]  = MFMA(Ahi, Bx[kt][nt],  ax[mt][nt],  0, 0, 0);
                    axx[mt][nt] = MFMA(Ahi, Bxx[kt][nt], axx[mt][nt], 0, 0, 0);
                }
            }
        }

        // phase A: t = tanh(z); stage hi/lo -> read new Bh frags
#pragma unroll
        for (int mt = 0; mt < 4; ++mt)
#pragma unroll
            for (int nt = 0; nt < 2; ++nt) {
                float t0 = fast_tanh(at[mt][nt][0]);
                float t1 = fast_tanh(at[mt][nt][1]);
                float t2 = fast_tanh(at[mt][nt][2]);
                float t3 = fast_tanh(at[mt][nt][3]);
                at[mt][nt][0] = t0; at[mt][nt][1] = t1;
                at[mt][nt][2] = t2; at[mt][nt][3] = t3;
                unsigned int h0 = pack_bf2(t0, t1);
                unsigned int h1 = pack_bf2(t2, t3);
                unsigned int l0 = pack_bf2(t0 - lo_f(h0), t1 - hi_f(h0));
                unsigned int l1 = pack_bf2(t2 - lo_f(h1), t3 - hi_f(h1));
                int off = ((nt * 16 + l15) * 128 + (mt * 16 + g * 4) * 2) ^ swz;
                *(uint2*)(st0 + off) = make_uint2(h0, h1);
                *(uint2*)(st1 + off) = make_uint2(l0, l1);
            }
        asm volatile("" ::: "memory");
#pragma unroll
        for (int kt = 0; kt < 2; ++kt)
#pragma unroll
            for (int nt = 0; nt < 2; ++nt) {
                int off = ((nt * 16 + l15) * 128 + (kt * 32 + g * 8) * 2) ^ swz;
                Bh_hi[kt][nt] = *(const bf16x8*)(st0 + off);
                Bh_lo[kt][nt] = *(const bf16x8*)(st1 + off);
            }
        asm volatile("" ::: "memory");

        // phase B: hx = s*zx ; hxx = s*zxx - 2*t*s*zx^2
#pragma unroll
        for (int mt = 0; mt < 4; ++mt)
#pragma unroll
            for (int nt = 0; nt < 2; ++nt) {
                float hx[4], hxx[4];
#pragma unroll
                for (int r = 0; r < 4; ++r) {
                    float t   = at[mt][nt][r];
                    float s   = fmaf(-t, t, 1.0f);
                    float zx  = ax[mt][nt][r];
                    float zxx = axx[mt][nt][r];
                    hx[r]  = s * zx;
                    hxx[r] = fmaf(s, zxx, -2.0f * t * zx * hx[r]);
                }
                unsigned int a0 = pack_bf2(hx[0], hx[1]);
                unsigned int a1 = pack_bf2(hx[2], hx[3]);
                unsigned int c0 = pack_bf2(hxx[0], hxx[1]);
                unsigned int c1 = pack_bf2(hxx[2], hxx[3]);
                int off = ((nt * 16 + l15) * 128 + (mt * 16 + g * 4) * 2) ^ swz;
                *(uint2*)(st0 + off) = make_uint2(a0, a1);
                *(uint2*)(st1 + off) = make_uint2(c0, c1);
            }
        asm volatile("" ::: "memory");
#pragma unroll
        for (int kt = 0; kt < 2; ++kt)
#pragma unroll
            for (int nt = 0; nt < 2; ++nt) {
                int off = ((nt * 16 + l15) * 128 + (kt * 32 + g * 8) * 2) ^ swz;
                Bx[kt][nt]  = *(const bf16x8*)(st0 + off);
                Bxx[kt][nt] = *(const bf16x8*)(st1 + off);
            }
        asm volatile("" ::: "memory");
    }

    // ---------- final layer 50 -> 100 + f (staged bf16, [samp][128j]) ----------
    const float lam1 = lam1p[0];
    const float el2  = __expf(lam2p[0]);
    const float dtv  = dtp[0];

    f32x4 u_all[7][2];

    // chunk A: q-tiles 0..3
    __syncthreads();
    prep_frags<4, 2, true, true>(wfrag, W5, HW, 0, Q, Q, tid);
    __syncthreads();
#pragma unroll
    for (int mtl = 0; mtl < 4; ++mtl) {
        f32x4 au[2], aux_[2], auxx[2];
#pragma unroll
        for (int nt = 0; nt < 2; ++nt) {
#pragma unroll
            for (int r = 0; r < 4; ++r) au[nt][r] = b5[mtl * 16 + g * 4 + r];
            aux_[nt] = Z4; auxx[nt] = Z4;
        }
#pragma unroll
        for (int kt = 0; kt < 2; ++kt) {
            bf16x8 Ahi = *(const bf16x8*)(wfl + (kt * 4 + mtl) * 1024);
            bf16x8 Alo = *(const bf16x8*)(wfl + (8 + kt * 4 + mtl) * 1024);
#pragma unroll
            for (int nt = 0; nt < 2; ++nt) {
                au[nt]   = MFMA(Ahi, Bh_hi[kt][nt], au[nt],   0, 0, 0);
                au[nt]   = MFMA(Ahi, Bh_lo[kt][nt], au[nt],   0, 0, 0);
                au[nt]   = MFMA(Alo, Bh_hi[kt][nt], au[nt],   0, 0, 0);
                aux_[nt] = MFMA(Ahi, Bx[kt][nt],  aux_[nt], 0, 0, 0);
                auxx[nt] = MFMA(Ahi, Bxx[kt][nt], auxx[nt], 0, 0, 0);
            }
        }
#pragma unroll
        for (int nt = 0; nt < 2; ++nt) {
            float fv[4];
#pragma unroll
            for (int r = 0; r < 4; ++r) {
                float u = au[nt][r];
                u_all[mtl][nt][r] = u;
                fv[r] = fmaf(-lam1 * u, aux_[nt][r], el2 * auxx[nt][r]);
            }
            unsigned int f0 = pack_bf2(fv[0], fv[1]);
            unsigned int f1 = pack_bf2(fv[2], fv[3]);
            int off = ((nt * 16 + l15) * 256 + (mtl * 16 + g * 4) * 2) ^ swz;
            *(uint2*)(st0 + off) = make_uint2(f0, f1);
        }
    }

    // chunk B: q-tiles 4..6
    __syncthreads();
    prep_frags<3, 2, true, true>(wfrag, W5, HW, 64, Q, Q, tid);
    __syncthreads();
#pragma unroll
    for (int mtl = 0; mtl < 3; ++mtl) {
        const int mtg = 4 + mtl;
        f32x4 au[2], aux_[2], auxx[2];
#pragma unroll
        for (int nt = 0; nt < 2; ++nt) {
#pragma unroll
            for (int r = 0; r < 4; ++r) {
                int q = 64 + mtl * 16 + g * 4 + r;
                au[nt][r] = (q < Q) ? b5[q] : 0.0f;
            }
            aux_[nt] = Z4; auxx[nt] = Z4;
        }
#pragma unroll
        for (int kt = 0; kt < 2; ++kt) {
            bf16x8 Ahi = *(const bf16x8*)(wfl + (kt * 3 + mtl) * 1024);
            bf16x8 Alo = *(const bf16x8*)(wfl + (6 + kt * 3 + mtl) * 1024);
#pragma unroll
            for (int nt = 0; nt < 2; ++nt) {
                au[nt]   = MFMA(Ahi, Bh_hi[kt][nt], au[nt],   0, 0, 0);
                au[nt]   = MFMA(Ahi, Bh_lo[kt][nt], au[nt],   0, 0, 0);
                au[nt]   = MFMA(Alo, Bh_hi[kt][nt], au[nt],   0, 0, 0);
                aux_[nt] = MFMA(Ahi, Bx[kt][nt],  aux_[nt], 0, 0, 0);
                auxx[nt] = MFMA(Ahi, Bxx[kt][nt], auxx[nt], 0, 0, 0);
            }
        }
#pragma unroll
        for (int nt = 0; nt < 2; ++nt) {
            float fv[4];
#pragma unroll
            for (int r = 0; r < 4; ++r) {
                int q = 64 + mtl * 16 + g * 4 + r;
                float u = au[nt][r];
                u_all[mtg][nt][r] = u;
                float f = fmaf(-lam1 * u, aux_[nt][r], el2 * auxx[nt][r]);
                fv[r] = (q < Q) ? f : 0.0f;
            }
            unsigned int f0 = pack_bf2(fv[0], fv[1]);
            unsigned int f1 = pack_bf2(fv[2], fv[3]);
            int off = ((nt * 16 + l15) * 256 + ((64 + mtl * 16) + g * 4) * 2) ^ swz;
            *(uint2*)(st0 + off) = make_uint2(f0, f1);
        }
    }
    asm volatile("" ::: "memory");

    // ---------- f B-frags; alpha GEMM + direct out stores ----------
    bf16x8 Ff[4][2];
#pragma unroll
    for (int kt = 0; kt < 4; ++kt)
#pragma unroll
        for (int nt = 0; nt < 2; ++nt) {
            int off = ((nt * 16 + l15) * 256 + (kt * 32 + g * 8) * 2) ^ swz;
            Ff[kt][nt] = *(const bf16x8*)(st0 + off);
        }
    asm volatile("" ::: "memory");
    {   // j = 112..127 never written (stale LDS): zero those B-frags (g>=2, kt=3)
        const bf16x8 z8 = {0, 0, 0, 0, 0, 0, 0, 0};
        if (g >= 2) { Ff[3][0] = z8; Ff[3][1] = z8; }
    }

    // alpha chunk A: q-tiles 0..3
    __syncthreads();
    prep_frags<4, 4, false, false>(wfrag, alpha, Q, 0, Q, Q, tid);
    __syncthreads();
#pragma unroll
    for (int mtl = 0; mtl < 4; ++mtl) {
        f32x4 ac[2]; ac[0] = Z4; ac[1] = Z4;
#pragma unroll
        for (int kt = 0; kt < 4; ++kt) {
            bf16x8 Aa = *(const bf16x8*)(wfl + (kt * 4 + mtl) * 1024);
#pragma unroll
            for (int nt = 0; nt < 2; ++nt)
                ac[nt] = MFMA(Aa, Ff[kt][nt], ac[nt], 0, 0, 0);
        }
#pragma unroll
        for (int nt = 0; nt < 2; ++nt) {
            f32x4 ov;
#pragma unroll
            for (int r = 0; r < 4; ++r)
                ov[r] = fmaf(-dtv, ac[nt][r], u_all[mtl][nt][r]);
            *(f32x4*)(&out[(size_t)(sbase + nt * 16 + l15) * Q + mtl * 16 + g * 4]) = ov;
        }
    }

    // alpha chunk B: q-tiles 4..6
    __syncthreads();
    prep_frags<3, 4, false, false>(wfrag, alpha, Q, 64, Q, Q, tid);
    __syncthreads();
#pragma unroll
    for (int mtl = 0; mtl < 3; ++mtl) {
        const int mtg = 4 + mtl;
        f32x4 ac[2]; ac[0] = Z4; ac[1] = Z4;
#pragma unroll
        for (int kt = 0; kt < 4; ++kt) {
            bf16x8 Aa = *(const bf16x8*)(wfl + (kt * 3 + mtl) * 1024);
#pragma unroll
            for (int nt = 0; nt < 2; ++nt)
                ac[nt] = MFMA(Aa, Ff[kt][nt], ac[nt], 0, 0, 0);
        }
        int qb = 64 + mtl * 16 + g * 4;
#pragma unroll
        for (int nt = 0; nt < 2; ++nt) {
            if (qb < Q) {
                f32x4 ov;
#pragma unroll
                for (int r = 0; r < 4; ++r)
                    ov[r] = fmaf(-dtv, ac[nt][r], u_all[mtg][nt][r]);
                *(f32x4*)(&out[(size_t)(sbase + nt * 16 + l15) * Q + qb]) = ov;
            }
        }
    }
}

extern "C" void kernel_launch(void* const* d_in, const int* in_sizes, int n_in,
                              void* d_out, int out_size, void* d_ws, size_t ws_size,
                              hipStream_t stream) {
    const float* W0 = (const float*)d_in[0];
    const float* b0 = (const float*)d_in[1];
    const float* W1 = (const float*)d_in[2];
    const float* b1 = (const float*)d_in[3];
    const float* W2 = (const float*)d_in[4];
    const float* b2 = (const float*)d_in[5];
    const float* W3 = (const float*)d_in[6];
    const float* b3 = (const float*)d_in[7];
    const float* W4 = (const float*)d_in[8];
    const float* b4 = (const float*)d_in[9];
    const float* W5 = (const float*)d_in[10];
    const float* b5 = (const float*)d_in[11];
    const float* x     = (const float*)d_in[12];
    const float* lam1  = (const float*)d_in[13];
    const float* lam2  = (const float*)d_in[14];
    const float* alpha = (const float*)d_in[15];
    const float* dt    = (const float*)d_in[16];

    pinn_mfma<<<NBLK, BLK, 0, stream>>>(W0, b0, W1, b1, W2, b2, W3, b3, W4, b4,
                                        W5, b5, x, lam1, lam2, alpha, dt,
                                        (float*)d_out);
}